// Round 6
// baseline (81.747 us; speedup 1.0000x reference)
//
#include <hip/hip_runtime.h>

#define GDIM 76
#define GG   5776
#define DDIM 85
#define ADIM 3
#define NCH  1615              // float4 chunks per tile = DDIM*GDIM/4 = 19*85
#define PLANE (DDIM * GG)      // 491360 floats per (b,a) slab (same for in & out)

// Async global->LDS DMA, 16B per lane, LDS dest linear (base + lane*16),
// global source per-lane (the transpose happens in the gather).
#define GLOAD_LDS16(gp, lp) __builtin_amdgcn_global_load_lds(                 \
    (const __attribute__((address_space(1))) void*)(gp),                      \
    (__attribute__((address_space(3))) void*)(lp), 16, 0, 0)

// One block per (b, a, i) slab-row. LDS chunk c holds input float4
// (d = c%85, k = c/85) of this row -> phase 2 reads chunk t = tid-flat
// linearly (conflict-free b128), activates (d uniform per quad), and emits
// lane-coalesced nontemporal stores at +85e immediate offsets.
__global__ __launch_bounds__(256, 6) void yolo_kernel(const float* __restrict__ x,
                                                      float* __restrict__ out) {
    // XCD swizzle: 7296 = 8 * 912, bijective.
    const int cpx = gridDim.x >> 3;
    const int blk = (blockIdx.x & 7) * cpx + (blockIdx.x >> 3);

    const int i    = blk % GDIM;
    const int slab = blk / GDIM;   // b*A + a
    const int a    = slab % ADIM;
    const int tid  = threadIdx.x;

    __shared__ __align__(16) float lds[NCH * 4];   // 25840 B -> 6 blocks/CU

    const float* __restrict__ src = x + (size_t)slab * PLANE + i * GDIM;

    // ---- phase 1: transpose-gather via async DMA (no VGPR data traffic) ----
    #pragma unroll
    for (int it = 0; it < 7; ++it) {
        const int c = tid + it * 256;
        if (it < 6 || c < NCH) {
            const int d = c % DDIM;            // channel (magic-mul)
            const int k = c / DDIM;            // float4 column
            GLOAD_LDS16(src + (size_t)d * GG + 4 * k, &lds[4 * c]);
        }
    }
    __syncthreads();   // compiler drains vmcnt(0) here; DMA landed

    const float aw  = (a == 0) ? 10.0f : (a == 1) ? 16.0f : 33.0f;
    const float ah  = (a == 0) ? 13.0f : (a == 1) ? 30.0f : 23.0f;
    const float fi8 = (float)i * 8.0f;

    float* __restrict__ dst = out + (size_t)slab * PLANE + i * (GDIM * DDIM);

    // ---- phase 2: linear b128 reads + d-uniform activation + nt stores ----
    #pragma unroll
    for (int it = 0; it < 7; ++it) {
        const int t = tid + it * 256;
        if (it < 6 || t < NCH) {
            const float4 v = *(const float4*)&lds[4 * t];
            const int d = t % DDIM;            // uniform across this quad
            const int q = t / DDIM;            // g = 4q + e

            const bool iswh = (d == 3) | (d == 4);
            const bool isx  = (d == 1);
            const bool isy  = (d == 2);
            const float A   = (d == 3) ? aw : ah;
            const float C   = (isx | isy) ? 8.0f : 1.0f;
            const float Bc  = isx ? fi8 : 0.0f;
            const float q32 = (float)(32 * q);

            float* p = dst + (340 * q + d);    // stores at +85e imm offsets
            const float vv[4] = {v.x, v.y, v.z, v.w};
            #pragma unroll
            for (int e = 0; e < 4; ++e) {
                const float val = vv[e];
                const float ev  = __expf(iswh ? val : -val);   // one exp/elem
                const float s   = __builtin_amdgcn_rcpf(1.0f + ev);
                const float B   = isy ? (q32 + (float)(8 * e)) : Bc;
                const float rs  = s * C + B;                   // fma
                const float r   = iswh ? ev * A : rs;
                __builtin_nontemporal_store(r, p + 85 * e);
            }
        }
    }
}

extern "C" void kernel_launch(void* const* d_in, const int* in_sizes, int n_in,
                              void* d_out, int out_size, void* d_ws, size_t ws_size,
                              hipStream_t stream) {
    const float* x = (const float*)d_in[0];
    float* out = (float*)d_out;
    const int B = in_sizes[0] / (ADIM * DDIM * GG);   // 32
    const int nblocks = B * ADIM * GDIM;              // 7296 = 8 * 912
    yolo_kernel<<<dim3(nblocks), dim3(256), 0, stream>>>(x, out);
}

// Round 7
// 74.001 us; speedup vs baseline: 1.1047x; 1.1047x over previous
//
#include <hip/hip_runtime.h>

#define GDIM 76
#define GG   5776
#define DDIM 85
#define ADIM 3
#define NCH  1615              // float4 chunks per tile = 19*85
#define ROWV4 19
#define PLANE (DDIM * GG)      // 491360 floats per (b,a) slab (in & out)

// One block per (b, a, i) slab-row. Phase 1: coalesced float4 global loads
// (round-5 pattern) + activation in registers + ONE ds_write_b128 per quad
// into chunk-transposed layout (chunk c = k*85 + d at byte 16c). Phase 2:
// linear conflict-free ds_read_b128 (chunk t), d = t%85 uniform per quad,
// 4 lane-coalesced nontemporal dword stores at +85e immediate offsets.
__global__ __launch_bounds__(256, 6) void yolo_kernel(const float* __restrict__ x,
                                                      float* __restrict__ out) {
    // XCD swizzle: 7296 = 8 * 912, bijective.
    const int cpx = gridDim.x >> 3;
    const int blk = (blockIdx.x & 7) * cpx + (blockIdx.x >> 3);

    const int i    = blk % GDIM;
    const int slab = blk / GDIM;   // b*A + a
    const int a    = slab % ADIM;
    const int tid  = threadIdx.x;

    __shared__ __align__(16) float lds[NCH * 4];   // 25840 B -> 6 blocks/CU

    const float aw  = (a == 0) ? 10.0f : (a == 1) ? 16.0f : 33.0f;
    const float ah  = (a == 0) ? 13.0f : (a == 1) ? 30.0f : 23.0f;
    const float fi8 = (float)i * 8.0f;

    const float* __restrict__ src = x + (size_t)slab * PLANE + i * GDIM;
    float* __restrict__ dst = out + (size_t)slab * PLANE + i * (GDIM * DDIM);

    // ---- phase 1a: issue ALL coalesced float4 loads back-to-back ----
    float4 v[7];
    #pragma unroll
    for (int it = 0; it < 7; ++it) {
        const int idx = tid + it * 256;
        if (it < 6 || idx < NCH) {
            const int d = idx / ROWV4;           // magic-mul div by 19
            const int k = idx - d * ROWV4;
            v[it] = *(const float4*)(src + (size_t)d * GG + 4 * k);
        }
    }

    // ---- phase 1b: activation + single b128 write to chunk k*85+d ----
    #pragma unroll
    for (int it = 0; it < 7; ++it) {
        const int idx = tid + it * 256;
        if (it < 6 || idx < NCH) {
            const int d = idx / ROWV4;
            const int k = idx - d * ROWV4;
            const bool iswh = (d == 3) | (d == 4);
            const bool isx  = (d == 1);
            const bool isy  = (d == 2);
            const float A   = (d == 3) ? aw : ah;
            const float C   = (isx | isy) ? 8.0f : 1.0f;
            const float Bc  = isx ? fi8 : 0.0f;
            const float gk8 = (float)(32 * k);
            const float vv[4] = {v[it].x, v[it].y, v[it].z, v[it].w};
            float4 r;
            float* rp = &r.x;
            #pragma unroll
            for (int e = 0; e < 4; ++e) {
                const float val = vv[e];
                const float ev  = __expf(iswh ? val : -val);   // one exp/elem
                const float s   = __builtin_amdgcn_rcpf(1.0f + ev);
                const float B   = isy ? (gk8 + (float)(8 * e)) : Bc;
                const float rs  = s * C + B;                   // fma
                rp[e] = iswh ? ev * A : rs;
            }
            *(float4*)&lds[4 * (k * DDIM + d)] = r;            // ds_write_b128
        }
    }
    __syncthreads();

    // ---- phase 2: linear b128 reads + lane-coalesced nt stores ----
    #pragma unroll
    for (int it = 0; it < 7; ++it) {
        const int t = tid + it * 256;
        if (it < 6 || t < NCH) {
            const float4 r = *(const float4*)&lds[4 * t];      // conflict-free
            const int d = t % DDIM;                            // magic-mul
            const int q = t / DDIM;
            float* p = dst + (340 * q + d);
            __builtin_nontemporal_store(r.x, p);
            __builtin_nontemporal_store(r.y, p + DDIM);
            __builtin_nontemporal_store(r.z, p + 2 * DDIM);
            __builtin_nontemporal_store(r.w, p + 3 * DDIM);
        }
    }
}

extern "C" void kernel_launch(void* const* d_in, const int* in_sizes, int n_in,
                              void* d_out, int out_size, void* d_ws, size_t ws_size,
                              hipStream_t stream) {
    const float* x = (const float*)d_in[0];
    float* out = (float*)d_out;
    const int B = in_sizes[0] / (ADIM * DDIM * GG);   // 32
    const int nblocks = B * ADIM * GDIM;              // 7296 = 8 * 912
    yolo_kernel<<<dim3(nblocks), dim3(256), 0, stream>>>(x, out);
}

// Round 8
// 65.650 us; speedup vs baseline: 1.2452x; 1.1272x over previous
//
#include <hip/hip_runtime.h>

#define GDIM 76
#define GG   5776
#define DDIM 85
#define ADIM 3
#define LDSW 77            // lane stride 77 ≡ 13 (mod 32) -> conflict-free scalar LDS access
#define NV4  1615          // = 19 * 85 = DDIM*GDIM/4
#define ROWV4 19
#define PLANE (DDIM * GG)
#define BLK  512
#define ITERS 4            // 3 full (tid+2*512 <= 1535 < 1615) + 1 tail (tid < 79)

// Round-5 structure (best: 64.7 us) with 512-thread blocks so residency is
// wave-capped at 4 blocks x 8 waves = 32/32 waves per CU (was 24/32 via the
// 26 KB LDS cap at 256 threads). All access patterns identical to round 5.
__global__ __launch_bounds__(BLK, 8) void yolo_kernel(const float* __restrict__ x,
                                                      float* __restrict__ out) {
    // XCD swizzle: 7296 = 8 * 912, bijective; each XCD owns 912 consecutive tiles.
    const int cpx = gridDim.x >> 3;
    const int blk = (blockIdx.x & 7) * cpx + (blockIdx.x >> 3);

    const int i    = blk % GDIM;
    const int slab = blk / GDIM;   // b*A + a
    const int a    = slab % ADIM;
    const int tid  = threadIdx.x;

    __shared__ float lds[DDIM * LDSW];   // 26180 B -> 4 blocks/CU (wave-capped)

    const float aw  = (a == 0) ? 10.0f : (a == 1) ? 16.0f : 33.0f;
    const float ah  = (a == 0) ? 13.0f : (a == 1) ? 30.0f : 23.0f;
    const float fi8 = (float)i * 8.0f;

    const float* __restrict__ src = x + (size_t)slab * PLANE + i * GDIM;
    float* __restrict__ dst = out + (size_t)slab * PLANE + (size_t)i * (GDIM * DDIM);

    // ---- phase 1a: issue ALL coalesced float4 loads back-to-back (max MLP) ----
    float4 v[ITERS];
    #pragma unroll
    for (int it = 0; it < ITERS; ++it) {
        const int idx = tid + it * BLK;
        if (it < 3 || idx < NV4) {
            const int d = idx / ROWV4;           // magic-mul div by 19
            const int k = idx - d * ROWV4;
            v[it] = *(const float4*)(src + (size_t)d * GG + 4 * k);
        }
    }

    // ---- phase 1b: activation + contiguous LDS writes (~2-way, near-free) ----
    #pragma unroll
    for (int it = 0; it < ITERS; ++it) {
        const int idx = tid + it * BLK;
        if (it < 3 || idx < NV4) {
            const int d = idx / ROWV4;
            const int k = idx - d * ROWV4;
            const bool iswh = (d == 3) | (d == 4);
            const bool isx  = (d == 1);
            const bool isy  = (d == 2);
            const float A   = (d == 3) ? aw : ah;
            const float C   = (isx | isy) ? 8.0f : 1.0f;
            const float Bc  = isx ? fi8 : 0.0f;
            const float gk8 = (float)(32 * k);
            const float vv[4] = {v[it].x, v[it].y, v[it].z, v[it].w};
            float r[4];
            #pragma unroll
            for (int e = 0; e < 4; ++e) {
                const float val = vv[e];
                const float ev  = __expf(iswh ? val : -val);   // one exp/elem
                const float s   = __builtin_amdgcn_rcpf(1.0f + ev);
                const float B   = isy ? (gk8 + (float)(8 * e)) : Bc;
                const float rs  = s * C + B;                   // fma
                r[e] = iswh ? ev * A : rs;
            }
            float* p = &lds[d * LDSW + 4 * k];
            p[0] = r[0]; p[1] = r[1]; p[2] = r[2]; p[3] = r[3];
        }
    }
    __syncthreads();

    // ---- phase 2a: batch ALL ds_reads (conflict-free: lane stride 77≡13) ----
    float r[ITERS][4];
    #pragma unroll
    for (int it = 0; it < ITERS; ++it) {
        const int t = tid + it * BLK;
        if (it < 3 || t < NV4) {
            const int g0   = t / DDIM;                   // magic-mul div by 85
            const int d    = t - g0 * DDIM;
            const int base = d * LDSW + g0;
            r[it][0] = lds[base];
            r[it][1] = lds[base + ROWV4];                // imm offsets 76/152/228 B
            r[it][2] = lds[base + 2 * ROWV4];
            r[it][3] = lds[base + 3 * ROWV4];
        }
    }

    // ---- phase 2b: coalesced nontemporal stores (full-line-per-instruction) ----
    #pragma unroll
    for (int it = 0; it < ITERS; ++it) {
        const int t = tid + it * BLK;
        if (it < 3 || t < NV4) {
            #pragma unroll
            for (int e = 0; e < 4; ++e)
                __builtin_nontemporal_store(r[it][e], dst + t + e * NV4);
        }
    }
}

extern "C" void kernel_launch(void* const* d_in, const int* in_sizes, int n_in,
                              void* d_out, int out_size, void* d_ws, size_t ws_size,
                              hipStream_t stream) {
    const float* x = (const float*)d_in[0];
    float* out = (float*)d_out;
    const int B = in_sizes[0] / (ADIM * DDIM * GG);   // 32
    const int nblocks = B * ADIM * GDIM;              // 7296 = 8 * 912
    yolo_kernel<<<dim3(nblocks), dim3(BLK), 0, stream>>>(x, out);
}